// Round 9
// baseline (74.072 us; speedup 1.0000x reference)
//
#include <hip/hip_runtime.h>
#include <cstdint>

#define NB 8
#define NBOX 8732
#define NCL 21
#define NCM1 20
#define LASTD 102
#define CONF_TH 0.5f
#define IOU_TH 0.45f
#define TOPK 200
#define MAXOUT 400     // reference row pitch (flat tie-break encoding)
#define SELCAP 200     // provably sufficient accept cap (== TOPK)
#define EMITN 256      // topk reads within-class ranks [0,256) only
#define NTASK (NB * NCM1)
#define THREADS 1024
#define NW 16
#define NIT 9          // ceil(8732/1024)
#define NBIN 2048
#define KPAD 8768      // 64*137 >= NBOX: counting-sorted keys always fit
#define NBATCH (KPAD / 64)

// Exact equivalence (proven): uni>0 && RN_f32(inter/uni) > 0.45f
//   <=>  (double)inter > MIDD*(double)uni   for our operand domain.
// MIDD = double(0.45f) + 2^-26 (midpoint above 0.45f; 0.45f mantissa even so
// midpoint rounds to 0.45f, not >). 25-bit x 24-bit f64 product is exact.
// The uni>0 guard is removable: no division occurs; for valid-valid pairs
// uni >= max(area) > 0; for pairs with an all-zero (invalid) box inter==0 and
// the compare is 0 > nonneg -> false. No NaN path exists.
#define MIDD ((double)IOU_TH + 0x1p-26)

struct SM {
    float4 selbox[SELCAP];        // 3.2 KB
    float4 cbox[2][64];           // 4 KB (staged next-batch candidate boxes)
    float selA[SELCAP];           // 0.8 KB
    float carea[2][64];           // 0.5 KB
    uint64_t selkey[SELCAP];      // 1.6 KB
    uint64_t keys[KPAD];          // 70.1 KB
    uint64_t vmask[2][64];        // 1 KB, double-buffered victim masks
    unsigned long long supW[2][NW];  // per-wave full-check ballots (slot 0 unused)
    int hist[NBIN];               // 8 KB
    int binstart[NBIN];           // 8 KB
    int wavetot[NW];
    int Mshare, nselshare, prevNshare, doneflag;
};  // ~98 KB

// IoU(>0.45): explicit RN ops + exact f64-product compare, bit-matching the
// host fp32 reference. Symmetric in (a,b).
__device__ __forceinline__ int iou_sup(float4 a, float aA, float4 b, float bA) {
    float x1 = fmaxf(a.x, b.x), y1 = fmaxf(a.y, b.y);
    float x2 = fminf(a.z, b.z), y2 = fminf(a.w, b.w);
    float iw = fmaxf(__fsub_rn(x2, x1), 0.0f);
    float ih = fmaxf(__fsub_rn(y2, y1), 0.0f);
    float inter = __fmul_rn(iw, ih);
    float uni = __fsub_rn(__fadd_rn(aA, bA), inter);
    return (double)inter > MIDD * (double)uni;
}

__device__ __forceinline__ float4 load_box(const float* __restrict__ img,
                                           int boxoff, uint64_t key) {
    if ((key >> 32) == 0) return make_float4(0.f, 0.f, 0.f, 0.f);
    uint32_t i = 0xFFFFFFFFu - (uint32_t)key;
    const float* bp = img + (size_t)i * LASTD + boxoff;
    return make_float4(bp[0], bp[1], bp[2], bp[3]);
}

__device__ __forceinline__ float box_area(float4 b) {
    return __fmul_rn(__fsub_rn(b.z, b.x), __fsub_rn(b.w, b.y));
}

// One block per (image, class): 2048-bin counting sort of all conf>0.5
// candidates into exact (score desc, idx asc) order, then a one-barrier-per-
// batch pipelined greedy scan: wave0 {delta-check cur + resolve cur} runs
// concurrently with waves 1-15 {vmask(next) + chunked early-exit full-check
// of next vs the accepted snapshot}. Exactly replicates the reference's
// argmax+suppress loop; SELCAP=200 cap is output-equivalent (see r7 proof).
__global__ __launch_bounds__(THREADS) void nms_per_class(const float* __restrict__ yp,
                                                         float* __restrict__ rows) {
    __shared__ SM sm;
    const int task = blockIdx.x;
    const int b = task / NCM1;
    const int cm1 = task % NCM1;
    const int tid = threadIdx.x;
    const int lane = tid & 63;
    const int wav = tid >> 6;
    const float* img = yp + (size_t)b * NBOX * LASTD;
    const int boxoff = NCL + 4 * cm1;

    // ---- phase 1: conf column loads (all 9 in flight) ----
    float confs[NIT];
    #pragma unroll
    for (int it = 0; it < NIT; ++it) {
        int idx = it * THREADS + tid;
        confs[it] = (idx < NBOX) ? img[(size_t)idx * LASTD + (1 + cm1)] : 0.0f;
    }
    sm.hist[tid] = 0; sm.hist[tid + THREADS] = 0;
    __syncthreads();

    // ---- phase 2: 2048-bin histogram (top 11 mantissa bits, conf in (0.5,1)) --
    #pragma unroll
    for (int it = 0; it < NIT; ++it) {
        int idx = it * THREADS + tid;
        if (idx < NBOX && confs[it] > CONF_TH) {
            int bin = (int)((__float_as_uint(confs[it]) - 0x3F000000u) >> 12);
            atomicAdd(&sm.hist[bin], 1);
        }
    }
    __syncthreads();

    // ---- phase 3: descending bin bases via suffix-sum over bin pairs ----
    int h0 = sm.hist[2 * tid], h1 = sm.hist[2 * tid + 1];
    int x = h0 + h1;
    int s = x;
    #pragma unroll
    for (int d = 1; d <= 32; d <<= 1) {
        int y = __shfl_down(s, d);
        if (lane + d < 64) s += y;
    }
    if (lane == 0) sm.wavetot[wav] = s;
    __syncthreads();
    int cross = 0;
    #pragma unroll
    for (int w = 0; w < NW; ++w)
        if (w > wav) cross += sm.wavetot[w];
    int Safter = cross + s - x;               // keys in bins strictly above
    sm.binstart[2 * tid + 1] = Safter;        // higher bin (higher score) first
    sm.binstart[2 * tid] = Safter + h1;
    if (tid == 0) sm.Mshare = cross + s;
    sm.hist[2 * tid] = 0; sm.hist[2 * tid + 1] = 0;  // reuse as scatter ctr
    __syncthreads();

    // ---- phase 4: scatter keys to bin regions ----
    #pragma unroll
    for (int it = 0; it < NIT; ++it) {
        int idx = it * THREADS + tid;
        if (idx < NBOX && confs[it] > CONF_TH) {
            uint32_t bits = __float_as_uint(confs[it]);
            int bin = (int)((bits - 0x3F000000u) >> 12);
            int slot = sm.binstart[bin] + atomicAdd(&sm.hist[bin], 1);
            sm.keys[slot] = ((uint64_t)bits << 32) |
                            (uint32_t)(0xFFFFFFFFu - (uint32_t)idx);
        }
    }
    __syncthreads();
    const int M = sm.Mshare;
    for (int m = M + tid; m < KPAD; m += THREADS) sm.keys[m] = 0;
    // ---- phase 5: per-bin insertion sort (2 bins/thread, ~2 keys/bin) ----
    for (int f = tid; f < NBIN; f += THREADS) {
        int s0 = sm.binstart[f], h = sm.hist[f];
        for (int i2 = 1; i2 < h; ++i2) {
            uint64_t key = sm.keys[s0 + i2];
            int j = i2 - 1;
            while (j >= 0 && sm.keys[s0 + j] < key) {
                sm.keys[s0 + j + 1] = sm.keys[s0 + j];
                --j;
            }
            sm.keys[s0 + j + 1] = key;
        }
    }
    __syncthreads();

    // ---- phase 6: one-barrier-per-batch pipelined greedy scan ----
    uint64_t keyC = sm.keys[lane];
    uint64_t keyN = sm.keys[64 + lane];
    float4 boxC = load_box(img, boxoff, keyC);
    float4 boxN = load_box(img, boxoff, keyN);
    float aC = box_area(boxC), aN = box_area(boxN);
    // prologue: vmask[0] (16-wave split), cbox[1]=batch1, supW=0
    {
        const bool vC0 = (keyC >> 32) != 0;
        #pragma unroll
        for (int tt = 0; tt < 4; ++tt) {
            int t = wav + tt * NW;
            float4 tb;
            tb.x = __shfl(boxC.x, t); tb.y = __shfl(boxC.y, t);
            tb.z = __shfl(boxC.z, t); tb.w = __shfl(boxC.w, t);
            float ta = __shfl(aC, t);
            unsigned long long vm =
                __ballot(vC0 && t < lane && iou_sup(boxC, aC, tb, ta));
            if (lane == t) sm.vmask[0][t] = vm;
        }
        if (wav == 1) { sm.cbox[1][lane] = boxN; sm.carea[1][lane] = aN; }
        if (tid < 2 * NW) ((unsigned long long*)sm.supW)[tid] = 0ull;
    }
    __syncthreads();

    int nsel = 0, prevN = 0;
    bool done = false;
    for (int i = 0; i < NBATCH && !done; ++i) {
        const int p = i & 1;
        if (wav == 0) {
            const bool vC = (keyC >> 32) != 0;
            // delta-check cur vs last resolve's accepts [prevN, nsel)
            int sup = 0;
            for (int j = prevN; j < nsel; ++j)
                sup |= iou_sup(boxC, aC, sm.selbox[j], sm.selA[j]);
            unsigned long long Ed = __ballot(sup);
            unsigned long long V = __ballot(vC);
            // combine the 15 full-check ballots (written last iteration)
            unsigned long long Ef = (lane < NW - 1) ? sm.supW[p][lane + 1] : 0ull;
            #pragma unroll
            for (int d = 1; d < NW; d <<= 1) Ef |= __shfl_xor(Ef, d);
            Ef = __shfl(Ef, 0);
            uint64_t vm = sm.vmask[p][lane];
            uint64_t alive = ~(Ef | Ed | ~V);
            uint64_t accm = 0;
            int cnt = nsel;
            while (alive && cnt < SELCAP) {
                int t = __ffsll((unsigned long long)alive) - 1;
                accm |= 1ull << t;
                cnt++;
                uint64_t vt = (uint64_t)__shfl((unsigned long long)vm, t);
                alive &= ~vt;
                alive &= ~(1ull << t);
            }
            if ((accm >> lane) & 1ull) {
                int pos = nsel + __popcll(accm & ((1ull << lane) - 1ull));
                sm.selbox[pos] = boxC;
                sm.selA[pos] = aC;
                sm.selkey[pos] = keyC;
            }
            if (lane == 0) {
                sm.nselshare = cnt;
                sm.prevNshare = nsel;
                sm.doneflag = (cnt >= SELCAP) || (V != ~0ull);
            }
        } else {
            const bool vN = (keyN >> 32) != 0;
            // vmask(batch i+1) -> vmask[p^1], 15-wave split (t mod 15 = wav-1)
            #pragma unroll
            for (int tt = 0; tt < 5; ++tt) {
                int t = (wav - 1) + tt * (NW - 1);
                if (t < 64) {
                    float4 tb;
                    tb.x = __shfl(boxN.x, t); tb.y = __shfl(boxN.y, t);
                    tb.z = __shfl(boxN.z, t); tb.w = __shfl(boxN.w, t);
                    float ta = __shfl(aN, t);
                    unsigned long long vm =
                        __ballot(vN && t < lane && iou_sup(boxN, aN, tb, ta));
                    if (lane == t) sm.vmask[p ^ 1][t] = vm;
                }
            }
            // chunked early-exit full-check of batch i+1 vs [0..nsel):
            // wave handles candidate c (staged in cbox), lanes = accepted boxes
            unsigned long long sb = 0;
            for (int c = wav - 1; c < 64; c += NW - 1) {
                float4 cb = sm.cbox[p ^ 1][c];
                float ca = sm.carea[p ^ 1][c];
                if (!(ca > 0.0f)) continue;          // invalid: wave-uniform skip
                bool supc = false;
                for (int j0 = 0; j0 < nsel && !supc; j0 += 64) {
                    int j = j0 + lane;
                    int hit = (j < nsel) ? iou_sup(cb, ca, sm.selbox[j], sm.selA[j]) : 0;
                    supc = __ballot(hit) != 0ull;    // wave-uniform early exit
                }
                if (supc) sb |= 1ull << c;
            }
            if (lane == 0) sm.supW[p ^ 1][wav] = sb;
        }
        // all waves: prefetch batch i+2; wave1 stages it into cbox[p]
        int f0 = (i + 2) * 64;
        uint64_t key2 = (f0 < KPAD) ? sm.keys[f0 + lane] : 0;
        float4 box2 = load_box(img, boxoff, key2);
        float a2 = box_area(box2);
        if (wav == 1) { sm.cbox[p][lane] = box2; sm.carea[p][lane] = a2; }
        __syncthreads();  // publish accepts, counters, vmask, supW, cbox
        nsel = sm.nselshare;
        prevN = sm.prevNshare;
        done = sm.doneflag != 0;
        keyC = keyN; boxC = boxN; aC = aN;
        keyN = key2; boxN = box2; aN = a2;
    }

    // ---- phase 7: emit ranks [0,256) (all topk reads); zeros past nsel ----
    float* out0 = rows + (size_t)task * MAXOUT * 7;
    for (int r = tid; r < EMITN; r += THREADS) {
        float* o = out0 + (size_t)r * 7;
        if (r < nsel) {
            uint64_t key = sm.selkey[r];
            uint32_t i = 0xFFFFFFFFu - (uint32_t)key;
            float4 bx = sm.selbox[r];
            o[0] = (float)(cm1 + 1);
            o[1] = __uint_as_float((uint32_t)(key >> 32));
            o[2] = bx.x;
            o[3] = bx.y;
            o[4] = bx.z;
            o[5] = bx.w;
            o[6] = img[(size_t)i * LASTD + (LASTD - 1)];
        } else {
            #pragma unroll
            for (int q = 0; q < 7; ++q) o[q] = 0.0f;
        }
    }
}

// One block per image: top-200 by (conf desc, flat idx asc) over 20*400 rows.
// Per-class lists are already sorted desc; top-200 never needs within-class
// rank >= 256, so: 32 lists x 256 keys, 5 rounds of pairwise bitonic top-256
// merges (max-combine + 8 merge stages), then gather the first 200 rows.
// Flat index keeps the reference's list*400+r encoding for exact tie order.
__global__ __launch_bounds__(THREADS) void topk_per_image(const float* __restrict__ rows,
                                                          float* __restrict__ out) {
    __shared__ uint64_t K[8192];
    const int b = blockIdx.x;
    const int tid = threadIdx.x;
    const float* rb = rows + (size_t)b * (NCM1 * MAXOUT) * 7;

    for (int xx = tid; xx < 8192; xx += THREADS) {
        int list = xx >> 8, r = xx & 255;
        uint64_t k = 0;
        if (list < NCM1) {
            int flat = list * MAXOUT + r;
            float conf = rb[(size_t)flat * 7 + 1];
            k = ((uint64_t)__float_as_uint(conf) << 32) |
                (uint32_t)(0xFFFFFFFFu - (uint32_t)flat);
        }
        K[xx] = k;
    }
    __syncthreads();

    for (int round = 0; round < 5; ++round) {
        int npairs = 16 >> round;
        int sep = 256 << round;
        for (int w = tid; w < npairs * 256; w += THREADS) {
            int p = w >> 8, t = w & 255;
            int A = p * 2 * sep;
            uint64_t a = K[A + t];
            uint64_t c = K[A + sep + 255 - t];
            K[A + t] = a > c ? a : c;
        }
        __syncthreads();
        for (int j = 128; j >= 1; j >>= 1) {
            for (int w = tid; w < npairs * 128; w += THREADS) {
                int p = w >> 7, q = w & 127;
                int t = ((q & ~(j - 1)) << 1) | (q & (j - 1));
                int A = p * 2 * sep;
                uint64_t x0 = K[A + t];
                uint64_t x1 = K[A + t + j];
                if (x0 < x1) { K[A + t] = x1; K[A + t + j] = x0; }
            }
            __syncthreads();
        }
    }

    if (tid < TOPK) {
        uint64_t key = K[tid];
        uint32_t flat = 0xFFFFFFFFu - (uint32_t)key;
        const float* src = rb + (size_t)flat * 7;
        float* o = out + ((size_t)b * TOPK + tid) * 7;
        #pragma unroll
        for (int q = 0; q < 7; ++q) o[q] = src[q];
    }
}

extern "C" void kernel_launch(void* const* d_in, const int* in_sizes, int n_in,
                              void* d_out, int out_size, void* d_ws, size_t ws_size,
                              hipStream_t stream) {
    const float* yp = (const float*)d_in[0];
    float* rows = (float*)d_ws;  // NTASK*400*7 floats = 1.792 MB scratch
    float* out = (float*)d_out;

    hipLaunchKernelGGL(nms_per_class, dim3(NTASK), dim3(THREADS), 0, stream, yp, rows);
    hipLaunchKernelGGL(topk_per_image, dim3(NB), dim3(THREADS), 0, stream, rows, out);
}